// Round 2
// baseline (919.815 us; speedup 1.0000x reference)
//
#include <hip/hip_runtime.h>

typedef short s16x8 __attribute__((ext_vector_type(8)));
typedef float f32x4 __attribute__((ext_vector_type(4)));
typedef float f32x4u __attribute__((ext_vector_type(4), aligned(4)));  // 4B-aligned vector load

#define DIM     512
#define BATCH   256
#define NTRI    131328          // (512*512+512)/2
#define FDIM    131840          // 512 + NTRI
#define KBLOCKS 2060            // FDIM / 64
#define BN      64
#define NTILES  8               // 512 / BN

__device__ __forceinline__ unsigned short f2bf(float f) {
  __bf16 h = (__bf16)f;                       // RNE hardware cvt
  return __builtin_bit_cast(unsigned short, h);
}

// ---------- setup: pair index table, p -> (i<<16|j), triu order ----------
__global__ void build_table(unsigned* __restrict__ table) {
  int i = blockIdx.x;                          // 0..511
  int base = i * DIM - (i * (i - 1)) / 2;
  int len = DIM - i;
  for (int t = threadIdx.x; t < len; t += blockDim.x)
    table[base + t] = ((unsigned)i << 16) | (unsigned)(i + t);
}

// ---------- fused quad-feature GEMM: partial[chunk] = feat[256,Kc] @ W[n0:n0+64,:]^T ----------
// X is f32 row-major [256][512] (x itself for layer 1, H for layer 2).
__global__ __launch_bounds__(512, 4)
void qgemm(const unsigned* __restrict__ table,
           const float* __restrict__ X,             // [256][512] f32
           const float* __restrict__ W,             // [512][131840] f32
           float* __restrict__ partial,             // [C][256][512]
           int C)
{
  __shared__ unsigned short As[BATCH * 64];         // 32 KB, XOR-swizzled 16B slots
  const int ntile = blockIdx.x & (NTILES - 1);
  const int chunk = blockIdx.x >> 3;
  const int kb0 = (KBLOCKS * chunk) / C;
  const int kb1 = (KBLOCKS * (chunk + 1)) / C;
  const int n0 = ntile * BN;
  const int tid = threadIdx.x;
  const int lane = tid & 63;
  const int wave = tid >> 6;
  const int wm = wave & 3;                          // 4 waves along M (64 rows each)
  const int wn = wave >> 2;                         // 2 waves along N (32 cols each)
  const int lm = lane & 15;
  const int lk = lane >> 4;

  const int m   = tid & 255;                        // staging row, fixed per thread
  const int s8b = tid >> 8;                         // staging slot base (0 or 1)
  const float* xrow = X + (size_t)m * DIM;

  f32x4 acc[4][2] = {};

  const float* wbase = W + (size_t)(n0 + wn * 32 + lm) * FDIM + lk * 8;

  for (int kb = kb0; kb < kb1; ++kb) {
    // ---- stage feature tile [256 x 64] bf16 into LDS ----
    #pragma unroll
    for (int it = 0; it < 4; ++it) {
      int s8 = s8b + it * 2;                        // 0..7
      int kg0 = kb * 64 + s8 * 8;
      float p[8];
      if (kg0 >= DIM) {                             // quadratic features
        int p0 = kg0 - DIM;
        unsigned t0 = table[p0];
        unsigned t7 = table[p0 + 7];
        if ((t0 >> 16) == (t7 >> 16)) {             // wave-uniform fast path: same i, j contiguous
          float xi = xrow[t0 >> 16];
          int j0 = (int)(t0 & 0xffffu);
          f32x4u a = *(const f32x4u*)(xrow + j0);
          f32x4u b = *(const f32x4u*)(xrow + j0 + 4);
          p[0] = xi * a[0]; p[1] = xi * a[1]; p[2] = xi * a[2]; p[3] = xi * a[3];
          p[4] = xi * b[0]; p[5] = xi * b[1]; p[6] = xi * b[2]; p[7] = xi * b[3];
        } else {                                    // run boundary (rare, wave-uniform)
          #pragma unroll
          for (int e = 0; e < 8; ++e) {
            unsigned ij = table[p0 + e];
            p[e] = xrow[ij >> 16] * xrow[ij & 0xffffu];
          }
        }
      } else {                                      // linear features (kb < 8 only)
        f32x4 a = *(const f32x4*)(xrow + kg0);
        f32x4 b = *(const f32x4*)(xrow + kg0 + 4);
        p[0] = a[0]; p[1] = a[1]; p[2] = a[2]; p[3] = a[3];
        p[4] = b[0]; p[5] = b[1]; p[6] = b[2]; p[7] = b[3];
      }
      uint4 pk;
      pk.x = (unsigned)f2bf(p[0]) | ((unsigned)f2bf(p[1]) << 16);
      pk.y = (unsigned)f2bf(p[2]) | ((unsigned)f2bf(p[3]) << 16);
      pk.z = (unsigned)f2bf(p[4]) | ((unsigned)f2bf(p[5]) << 16);
      pk.w = (unsigned)f2bf(p[6]) | ((unsigned)f2bf(p[7]) << 16);
      int slot = s8 ^ (m & 7);                      // bank-conflict swizzle
      *(uint4*)((char*)As + m * 128 + slot * 16) = pk;
    }
    __syncthreads();

    // ---- compute: 2 k-steps of 32, 4x2 fragments per wave ----
    #pragma unroll
    for (int ks = 0; ks < 2; ++ks) {
      s16x8 bfr[2];
      #pragma unroll
      for (int nf = 0; nf < 2; ++nf) {
        const float* wp = wbase + (size_t)nf * 16 * FDIM + kb * 64 + ks * 32;
        f32x4 w0 = *(const f32x4*)wp;
        f32x4 w1 = *(const f32x4*)(wp + 4);
        uint4 pk;
        pk.x = (unsigned)f2bf(w0[0]) | ((unsigned)f2bf(w0[1]) << 16);
        pk.y = (unsigned)f2bf(w0[2]) | ((unsigned)f2bf(w0[3]) << 16);
        pk.z = (unsigned)f2bf(w1[0]) | ((unsigned)f2bf(w1[1]) << 16);
        pk.w = (unsigned)f2bf(w1[2]) | ((unsigned)f2bf(w1[3]) << 16);
        bfr[nf] = __builtin_bit_cast(s16x8, pk);
      }
      s16x8 afr[4];
      #pragma unroll
      for (int mf = 0; mf < 4; ++mf) {
        int mm = wm * 64 + mf * 16 + lm;
        int slot = (ks * 4 + lk) ^ (mm & 7);
        afr[mf] = *(const s16x8*)((const char*)As + mm * 128 + slot * 16);
      }
      #pragma unroll
      for (int mf = 0; mf < 4; ++mf)
        #pragma unroll
        for (int nf = 0; nf < 2; ++nf)
          acc[mf][nf] = __builtin_amdgcn_mfma_f32_16x16x32_bf16(afr[mf], bfr[nf], acc[mf][nf], 0, 0, 0);
    }
    __syncthreads();
  }

  // ---- write partial tile ----
  float* pout = partial + (size_t)chunk * (BATCH * DIM);
  #pragma unroll
  for (int mf = 0; mf < 4; ++mf) {
    #pragma unroll
    for (int nf = 0; nf < 2; ++nf) {
      int mrow = wm * 64 + mf * 16 + lk * 4;        // C/D: col=lane&15, row=(lane>>4)*4+reg
      int ncol = n0 + wn * 32 + nf * 16 + lm;
      #pragma unroll
      for (int r = 0; r < 4; ++r)
        pout[(size_t)(mrow + r) * DIM + ncol] = acc[mf][nf][r];
    }
  }
}

// ---------- reductions ----------
__global__ void reduce_h(const float* __restrict__ partial, const float* __restrict__ bias,
                         float* __restrict__ H, int C) {
  int t = blockIdx.x * blockDim.x + threadIdx.x;   // 131072, t = m*512 + o
  int o = t & (DIM - 1);
  float s = bias[o];
  #pragma unroll 4
  for (int c = 0; c < C; ++c) s += partial[(size_t)c * (BATCH * DIM) + t];
  H[t] = s;                                        // f32 row-major [256][512], same layout as x
}

__global__ void reduce_out(const float* __restrict__ partial, const float* __restrict__ bias,
                           float* __restrict__ out, int C) {
  int t = blockIdx.x * blockDim.x + threadIdx.x;   // 131072
  int o = t & (DIM - 1);
  float s = bias[o];
  #pragma unroll 4
  for (int c = 0; c < C; ++c) s += partial[(size_t)c * (BATCH * DIM) + t];
  out[t] = s;
}

extern "C" void kernel_launch(void* const* d_in, const int* in_sizes, int n_in,
                              void* d_out, int out_size, void* d_ws, size_t ws_size,
                              hipStream_t stream) {
  const float* x  = (const float*)d_in[0];
  const float* W0 = (const float*)d_in[1];
  const float* b0 = (const float*)d_in[2];
  const float* W1 = (const float*)d_in[3];
  const float* b1 = (const float*)d_in[4];
  float* out = (float*)d_out;

  char* ws = (char*)d_ws;
  unsigned* table = (unsigned*)ws;                           // 525,312 B
  float* H        = (float*)(ws + 525312);                   // 524,288 B
  float* partial  = (float*)(ws + 1049600);                  // C * 512 KiB

  size_t avail = (ws_size > 1049600) ? (ws_size - 1049600) : 0;
  int C = (int)(avail / ((size_t)BATCH * DIM * sizeof(float)));
  if (C > 64) C = 64;
  if (C < 1)  C = 1;

  build_table<<<dim3(512), dim3(256), 0, stream>>>(table);

  qgemm<<<dim3(NTILES * C), dim3(512), 0, stream>>>(table, x, W0, partial, C);
  reduce_h<<<dim3(512), dim3(256), 0, stream>>>(partial, b0, H, C);

  qgemm<<<dim3(NTILES * C), dim3(512), 0, stream>>>(table, H, W1, partial, C);
  reduce_out<<<dim3(512), dim3(256), 0, stream>>>(partial, b1, out, C);
}

// Round 3
// 431.540 us; speedup vs baseline: 2.1315x; 2.1315x over previous
//
#include <hip/hip_runtime.h>

typedef short s16x4 __attribute__((ext_vector_type(4)));
typedef short s16x8 __attribute__((ext_vector_type(8)));
typedef float f32x4 __attribute__((ext_vector_type(4)));

#define DIM     512
#define BATCH   256
#define NTRI    131328          // (512*512+512)/2
#define FDIM    131840          // 512 + NTRI
#define KBLOCKS 2060            // FDIM / 64
#define BN      64
#define NTILES  8               // 512 / BN

__device__ __forceinline__ unsigned short f2bf(float f) {
  __bf16 h = (__bf16)f;                       // RNE hardware cvt
  return __builtin_bit_cast(unsigned short, h);
}
__device__ __forceinline__ float bf2f(unsigned short s) {
  union { unsigned u; float f; } v; v.u = (unsigned)s << 16; return v.f;
}
__device__ __forceinline__ int swz(int m) { return (m ^ (m >> 3)) & 7; }

// ---------- setup: pair index table, p -> (i<<16|j), triu order ----------
__global__ void build_table(unsigned* __restrict__ table) {
  int i = blockIdx.x;                          // 0..511
  int base = i * DIM - (i * (i - 1)) / 2;
  int len = DIM - i;
  for (int t = threadIdx.x; t < len; t += blockDim.x)
    table[base + t] = ((unsigned)i << 16) | (unsigned)(i + t);
}

// ---------- setup: x[256][512] f32 -> Xt[512][256] bf16 ----------
__global__ void transpose_x(const float* __restrict__ x, unsigned short* __restrict__ Xt) {
  int t = blockIdx.x * blockDim.x + threadIdx.x;   // 131072
  int r = t & (BATCH - 1);
  int c = t >> 8;
  Xt[c * BATCH + r] = f2bf(x[r * DIM + c]);
}

// ---------- fused quad-feature GEMM: partial[chunk] = feat[256,Kc] @ W[n0:n0+64,:]^T ----------
// Xt is bf16 [512][256] (feature-source transposed: column m = batch row).
__global__ __launch_bounds__(512, 4)
void qgemm(const unsigned* __restrict__ table,
           const unsigned short* __restrict__ Xt,   // [512][256] bf16
           const float* __restrict__ W,             // [512][131840] f32
           float* __restrict__ partial,             // [C][256][512]
           int C)
{
  __shared__ unsigned short As[BATCH * 64];         // 32 KB, XOR-swizzled 16B slots
  const int ntile = blockIdx.x & (NTILES - 1);
  const int chunk = blockIdx.x >> 3;
  const int kb0 = (KBLOCKS * chunk) / C;
  const int kb1 = (KBLOCKS * (chunk + 1)) / C;
  const int n0 = ntile * BN;
  const int tid = threadIdx.x;
  const int lane = tid & 63;
  const int wave = tid >> 6;
  const int wm = wave & 3;                          // 4 waves along M (64 rows each)
  const int wn = wave >> 2;                         // 2 waves along N (32 cols each)
  const int lm = lane & 15;
  const int lk = lane >> 4;

  // staging role: wave = k-group s8 (wave-uniform!), lane owns 4 batch rows
  const int s8 = wave;                              // 0..7
  const int m0 = lane * 4;                          // 0..252

  f32x4 acc[4][2] = {};

  const float* wbase = W + (size_t)(n0 + wn * 32 + lm) * FDIM + lk * 8;

  for (int kb = kb0; kb < kb1; ++kb) {
    // ---- stage feature tile [256 x 64] bf16 into LDS (coalesced 8B column loads) ----
    {
      int f0 = kb * 64 + s8 * 8;
      unsigned w4[4][4];                            // [mm][wordpair] -> uint4 per row
      bool linear = (f0 < DIM);
      if (linear) {                                 // kb < 8 only
        s16x4 xj[8];
        #pragma unroll
        for (int e = 0; e < 8; ++e)
          xj[e] = *(const s16x4*)(Xt + (f0 + e) * BATCH + m0);
        #pragma unroll
        for (int ep = 0; ep < 4; ++ep)
          #pragma unroll
          for (int mm = 0; mm < 4; ++mm)
            w4[mm][ep] = (unsigned)(unsigned short)xj[2*ep][mm]
                       | ((unsigned)(unsigned short)xj[2*ep+1][mm] << 16);
      } else {
        int p0 = f0 - DIM;
        unsigned t0 = table[p0];
        unsigned t7 = table[p0 + 7];
        if ((t0 >> 16) == (t7 >> 16)) {             // fast path: same i, j contiguous
          int i = (int)(t0 >> 16), j0 = (int)(t0 & 0xffffu);
          s16x4 xi = *(const s16x4*)(Xt + i * BATCH + m0);
          s16x4 xj[8];
          #pragma unroll
          for (int e = 0; e < 8; ++e)
            xj[e] = *(const s16x4*)(Xt + (j0 + e) * BATCH + m0);
          float xif[4];
          #pragma unroll
          for (int mm = 0; mm < 4; ++mm) xif[mm] = bf2f((unsigned short)xi[mm]);
          #pragma unroll
          for (int ep = 0; ep < 4; ++ep)
            #pragma unroll
            for (int mm = 0; mm < 4; ++mm) {
              float a = xif[mm] * bf2f((unsigned short)xj[2*ep][mm]);
              float b = xif[mm] * bf2f((unsigned short)xj[2*ep+1][mm]);
              w4[mm][ep] = (unsigned)f2bf(a) | ((unsigned)f2bf(b) << 16);
            }
        } else {                                    // run boundary (rare, wave-uniform)
          #pragma unroll
          for (int ep = 0; ep < 4; ++ep) {
            unsigned ta = table[p0 + 2*ep], tb = table[p0 + 2*ep + 1];
            s16x4 xia = *(const s16x4*)(Xt + (ta >> 16) * BATCH + m0);
            s16x4 xja = *(const s16x4*)(Xt + (ta & 0xffffu) * BATCH + m0);
            s16x4 xib = *(const s16x4*)(Xt + (tb >> 16) * BATCH + m0);
            s16x4 xjb = *(const s16x4*)(Xt + (tb & 0xffffu) * BATCH + m0);
            #pragma unroll
            for (int mm = 0; mm < 4; ++mm) {
              float a = bf2f((unsigned short)xia[mm]) * bf2f((unsigned short)xja[mm]);
              float b = bf2f((unsigned short)xib[mm]) * bf2f((unsigned short)xjb[mm]);
              w4[mm][ep] = (unsigned)f2bf(a) | ((unsigned)f2bf(b) << 16);
            }
          }
        }
      }
      // 8x4 micro-tile now in registers; write 4 swizzled 16B rows
      #pragma unroll
      for (int mm = 0; mm < 4; ++mm) {
        int m = m0 + mm;
        int slot = s8 ^ swz(m);
        uint4 pk = make_uint4(w4[mm][0], w4[mm][1], w4[mm][2], w4[mm][3]);
        *(uint4*)((char*)As + m * 128 + slot * 16) = pk;
      }
    }
    __syncthreads();

    // ---- compute: 2 k-steps of 32, 4x2 fragments per wave ----
    #pragma unroll
    for (int ks = 0; ks < 2; ++ks) {
      s16x8 bfr[2];
      #pragma unroll
      for (int nf = 0; nf < 2; ++nf) {
        const float* wp = wbase + (size_t)nf * 16 * FDIM + kb * 64 + ks * 32;
        f32x4 w0 = *(const f32x4*)wp;
        f32x4 w1 = *(const f32x4*)(wp + 4);
        uint4 pk;
        pk.x = (unsigned)f2bf(w0[0]) | ((unsigned)f2bf(w0[1]) << 16);
        pk.y = (unsigned)f2bf(w0[2]) | ((unsigned)f2bf(w0[3]) << 16);
        pk.z = (unsigned)f2bf(w1[0]) | ((unsigned)f2bf(w1[1]) << 16);
        pk.w = (unsigned)f2bf(w1[2]) | ((unsigned)f2bf(w1[3]) << 16);
        bfr[nf] = __builtin_bit_cast(s16x8, pk);
      }
      s16x8 afr[4];
      #pragma unroll
      for (int mf = 0; mf < 4; ++mf) {
        int mm = wm * 64 + mf * 16 + lm;
        int slot = (ks * 4 + lk) ^ swz(mm);
        afr[mf] = *(const s16x8*)((const char*)As + mm * 128 + slot * 16);
      }
      #pragma unroll
      for (int mf = 0; mf < 4; ++mf)
        #pragma unroll
        for (int nf = 0; nf < 2; ++nf)
          acc[mf][nf] = __builtin_amdgcn_mfma_f32_16x16x32_bf16(afr[mf], bfr[nf], acc[mf][nf], 0, 0, 0);
    }
    __syncthreads();
  }

  // ---- write partial tile ----
  float* pout = partial + (size_t)chunk * (BATCH * DIM);
  #pragma unroll
  for (int mf = 0; mf < 4; ++mf) {
    #pragma unroll
    for (int nf = 0; nf < 2; ++nf) {
      int mrow = wm * 64 + mf * 16 + lk * 4;        // C/D: col=lane&15, row=(lane>>4)*4+reg
      int ncol = n0 + wn * 32 + nf * 16 + lm;
      #pragma unroll
      for (int r = 0; r < 4; ++r)
        pout[(size_t)(mrow + r) * DIM + ncol] = acc[mf][nf][r];
    }
  }
}

// ---------- reductions ----------
__global__ void reduce_h(const float* __restrict__ partial, const float* __restrict__ bias,
                         unsigned short* __restrict__ Ht, int C) {
  int t = blockIdx.x * blockDim.x + threadIdx.x;   // 131072, t = b*512 + o
  int b = t >> 9;
  int o = t & (DIM - 1);
  float s = bias[o];
  #pragma unroll 4
  for (int c = 0; c < C; ++c) s += partial[(size_t)c * (BATCH * DIM) + t];
  Ht[o * BATCH + b] = f2bf(s);                     // transposed bf16 for layer-2 staging
}

__global__ void reduce_out(const float* __restrict__ partial, const float* __restrict__ bias,
                           float* __restrict__ out, int C) {
  int t = blockIdx.x * blockDim.x + threadIdx.x;   // 131072
  int o = t & (DIM - 1);
  float s = bias[o];
  #pragma unroll 4
  for (int c = 0; c < C; ++c) s += partial[(size_t)c * (BATCH * DIM) + t];
  out[t] = s;
}

extern "C" void kernel_launch(void* const* d_in, const int* in_sizes, int n_in,
                              void* d_out, int out_size, void* d_ws, size_t ws_size,
                              hipStream_t stream) {
  const float* x  = (const float*)d_in[0];
  const float* W0 = (const float*)d_in[1];
  const float* b0 = (const float*)d_in[2];
  const float* W1 = (const float*)d_in[3];
  const float* b1 = (const float*)d_in[4];
  float* out = (float*)d_out;

  char* ws = (char*)d_ws;
  unsigned* table    = (unsigned*)ws;                        // 525,312 B
  unsigned short* Xt = (unsigned short*)(ws + 525312);       // 262,144 B
  unsigned short* Ht = (unsigned short*)(ws + 787456);       // 262,144 B
  float* partial     = (float*)(ws + 1049600);               // C * 512 KiB

  size_t avail = (ws_size > 1049600) ? (ws_size - 1049600) : 0;
  int C = (int)(avail / ((size_t)BATCH * DIM * sizeof(float)));
  if (C > 64) C = 64;
  if (C < 1)  C = 1;

  build_table<<<dim3(512), dim3(256), 0, stream>>>(table);
  transpose_x<<<dim3(512), dim3(256), 0, stream>>>(x, Xt);

  qgemm<<<dim3(NTILES * C), dim3(512), 0, stream>>>(table, Xt, W0, partial, C);
  reduce_h<<<dim3(512), dim3(256), 0, stream>>>(partial, b0, Ht, C);

  qgemm<<<dim3(NTILES * C), dim3(512), 0, stream>>>(table, Ht, W1, partial, C);
  reduce_out<<<dim3(512), dim3(256), 0, stream>>>(partial, b1, out, C);
}

// Round 4
// 254.996 us; speedup vs baseline: 3.6072x; 1.6923x over previous
//
#include <hip/hip_runtime.h>

typedef short s16x4 __attribute__((ext_vector_type(4)));
typedef short s16x8 __attribute__((ext_vector_type(8)));
typedef float f32x4 __attribute__((ext_vector_type(4)));

#define DIM     512
#define BATCH   256
#define NTRI    131328          // (512*512+512)/2
#define FDIM    131840          // 512 + NTRI
#define KBLOCKS 2060            // FDIM / 64
#define BN      64
#define NTILES  8               // 512 / BN
#define CMAX    128

__device__ __forceinline__ unsigned short f2bf(float f) {
  __bf16 h = (__bf16)f;                       // RNE hardware cvt
  return __builtin_bit_cast(unsigned short, h);
}
__device__ __forceinline__ float bf2f(unsigned short s) {
  union { unsigned u; float f; } v; v.u = (unsigned)s << 16; return v.f;
}
// bijective on aligned 8-runs (read: rows r..r+15) AND on m=4*lane+mm (write)
__device__ __forceinline__ int swz(int m) { return (m ^ (m >> 2)) & 7; }

// ---------- setup: pair index table, p -> (i<<16|j), triu order ----------
__global__ void build_table(unsigned* __restrict__ table) {
  int i = blockIdx.x;                          // 0..511
  int base = i * DIM - (i * (i - 1)) / 2;
  int len = DIM - i;
  for (int t = threadIdx.x; t < len; t += blockDim.x)
    table[base + t] = ((unsigned)i << 16) | (unsigned)(i + t);
}

// ---------- setup: x[256][512] f32 -> Xt[512][256] bf16 ----------
__global__ void transpose_x(const float* __restrict__ x, unsigned short* __restrict__ Xt) {
  int t = blockIdx.x * blockDim.x + threadIdx.x;   // 131072
  int r = t & (BATCH - 1);
  int c = t >> 8;
  Xt[c * BATCH + r] = f2bf(x[r * DIM + c]);
}

// ---------- fused quad-feature GEMM: partial[chunk] = feat[256,Kc] @ W[n0:n0+64,:]^T ----------
__global__ __launch_bounds__(512, 4)
void qgemm(const unsigned* __restrict__ table,
           const unsigned short* __restrict__ Xt,   // [512][256] bf16
           const float* __restrict__ W,             // [512][131840] f32
           float* __restrict__ partial,             // [C][256][512]
           int C)
{
  __shared__ unsigned short As[BATCH * 64];         // 32 KB feature tile
  __shared__ unsigned short Ws[64 * 64];            //  8 KB weight tile (bf16)
  const int ntile = blockIdx.x & (NTILES - 1);
  const int chunk = blockIdx.x >> 3;
  const int kb0 = (KBLOCKS * chunk) / C;
  const int kb1 = (KBLOCKS * (chunk + 1)) / C;
  const int n0 = ntile * BN;
  const int tid = threadIdx.x;
  const int lane = tid & 63;
  const int wave = tid >> 6;
  const int wm = wave & 3;                          // 4 waves along M (64 rows each)
  const int wn = wave >> 2;                         // 2 waves along N (32 cols each)
  const int lm = lane & 15;
  const int lk = lane >> 4;

  // As staging role: wave = k-group s8 (wave-uniform table idx), lane owns 4 batch rows
  const int s8 = wave;                              // 0..7
  const int m0 = lane * 4;                          // 0..252
  // Ws staging role: 16 lanes cover 256B contiguous of one W row
  const int wr0 = tid >> 4;                         // 0..31 (+32 on 2nd iter)
  const int wc16 = tid & 15;                        // 16B unit within row-chunk

  f32x4 acc[4][2] = {};

  for (int kb = kb0; kb < kb1; ++kb) {
    // ---- issue W-tile loads first (longest latency), fully coalesced ----
    f32x4 wreg[2];
    #pragma unroll
    for (int it = 0; it < 2; ++it)
      wreg[it] = *(const f32x4*)(W + (size_t)(n0 + wr0 + it * 32) * FDIM + kb * 64 + wc16 * 4);

    // ---- stage feature tile [256 x 64] bf16 into LDS (coalesced 8B column loads) ----
    {
      int f0 = kb * 64 + s8 * 8;
      unsigned w4[4][4];                            // [mm][wordpair]
      if (f0 < DIM) {                               // linear features (kb < 8 only)
        s16x4 xj[8];
        #pragma unroll
        for (int e = 0; e < 8; ++e)
          xj[e] = *(const s16x4*)(Xt + (f0 + e) * BATCH + m0);
        #pragma unroll
        for (int ep = 0; ep < 4; ++ep)
          #pragma unroll
          for (int mm = 0; mm < 4; ++mm)
            w4[mm][ep] = (unsigned)(unsigned short)xj[2*ep][mm]
                       | ((unsigned)(unsigned short)xj[2*ep+1][mm] << 16);
      } else {
        int p0 = f0 - DIM;
        unsigned t0 = table[p0];
        unsigned t7 = table[p0 + 7];
        if ((t0 >> 16) == (t7 >> 16)) {             // fast path: same i, j contiguous
          int i = (int)(t0 >> 16), j0 = (int)(t0 & 0xffffu);
          s16x4 xi = *(const s16x4*)(Xt + i * BATCH + m0);
          s16x4 xj[8];
          #pragma unroll
          for (int e = 0; e < 8; ++e)
            xj[e] = *(const s16x4*)(Xt + (j0 + e) * BATCH + m0);
          float xif[4];
          #pragma unroll
          for (int mm = 0; mm < 4; ++mm) xif[mm] = bf2f((unsigned short)xi[mm]);
          #pragma unroll
          for (int ep = 0; ep < 4; ++ep)
            #pragma unroll
            for (int mm = 0; mm < 4; ++mm) {
              float a = xif[mm] * bf2f((unsigned short)xj[2*ep][mm]);
              float b = xif[mm] * bf2f((unsigned short)xj[2*ep+1][mm]);
              w4[mm][ep] = (unsigned)f2bf(a) | ((unsigned)f2bf(b) << 16);
            }
        } else {                                    // run boundary (rare, wave-uniform)
          #pragma unroll
          for (int ep = 0; ep < 4; ++ep) {
            unsigned ta = table[p0 + 2*ep], tb = table[p0 + 2*ep + 1];
            s16x4 xia = *(const s16x4*)(Xt + (ta >> 16) * BATCH + m0);
            s16x4 xja = *(const s16x4*)(Xt + (ta & 0xffffu) * BATCH + m0);
            s16x4 xib = *(const s16x4*)(Xt + (tb >> 16) * BATCH + m0);
            s16x4 xjb = *(const s16x4*)(Xt + (tb & 0xffffu) * BATCH + m0);
            #pragma unroll
            for (int mm = 0; mm < 4; ++mm) {
              float a = bf2f((unsigned short)xia[mm]) * bf2f((unsigned short)xja[mm]);
              float b = bf2f((unsigned short)xib[mm]) * bf2f((unsigned short)xjb[mm]);
              w4[mm][ep] = (unsigned)f2bf(a) | ((unsigned)f2bf(b) << 16);
            }
          }
        }
      }
      #pragma unroll
      for (int mm = 0; mm < 4; ++mm) {
        int m = m0 + mm;
        int slot = s8 ^ swz(m);
        uint4 pk = make_uint4(w4[mm][0], w4[mm][1], w4[mm][2], w4[mm][3]);
        *(uint4*)((char*)As + m * 128 + slot * 16) = pk;
      }
    }

    // ---- convert + store W tile (bf16, swizzled) ----
    #pragma unroll
    for (int it = 0; it < 2; ++it) {
      int r = wr0 + it * 32;
      unsigned lo = (unsigned)f2bf(wreg[it][0]) | ((unsigned)f2bf(wreg[it][1]) << 16);
      unsigned hi = (unsigned)f2bf(wreg[it][2]) | ((unsigned)f2bf(wreg[it][3]) << 16);
      int slot = (wc16 >> 1) ^ swz(r);
      *(uint2*)((char*)Ws + r * 128 + slot * 16 + (wc16 & 1) * 8) = make_uint2(lo, hi);
    }
    __syncthreads();

    // ---- compute: 2 k-steps of 32, 4x2 fragments per wave, all from LDS ----
    #pragma unroll
    for (int ks = 0; ks < 2; ++ks) {
      s16x8 bfr[2], afr[4];
      #pragma unroll
      for (int nf = 0; nf < 2; ++nf) {
        int n = wn * 32 + nf * 16 + lm;
        int slot = (ks * 4 + lk) ^ swz(n);
        bfr[nf] = *(const s16x8*)((const char*)Ws + n * 128 + slot * 16);
      }
      #pragma unroll
      for (int mf = 0; mf < 4; ++mf) {
        int mm = wm * 64 + mf * 16 + lm;
        int slot = (ks * 4 + lk) ^ swz(mm);
        afr[mf] = *(const s16x8*)((const char*)As + mm * 128 + slot * 16);
      }
      #pragma unroll
      for (int mf = 0; mf < 4; ++mf)
        #pragma unroll
        for (int nf = 0; nf < 2; ++nf)
          acc[mf][nf] = __builtin_amdgcn_mfma_f32_16x16x32_bf16(afr[mf], bfr[nf], acc[mf][nf], 0, 0, 0);
    }
    __syncthreads();
  }

  // ---- write partial tile ----
  float* pout = partial + (size_t)chunk * (BATCH * DIM);
  #pragma unroll
  for (int mf = 0; mf < 4; ++mf) {
    #pragma unroll
    for (int nf = 0; nf < 2; ++nf) {
      int mrow = wm * 64 + mf * 16 + lk * 4;        // C/D: col=lane&15, row=(lane>>4)*4+reg
      int ncol = n0 + wn * 32 + nf * 16 + lm;
      #pragma unroll
      for (int r = 0; r < 4; ++r)
        pout[(size_t)(mrow + r) * DIM + ncol] = acc[mf][nf][r];
    }
  }
}

// ---------- reductions ----------
__global__ void reduce_h(const float* __restrict__ partial, const float* __restrict__ bias,
                         unsigned short* __restrict__ Ht, int C) {
  int t = blockIdx.x * blockDim.x + threadIdx.x;   // 131072, t = b*512 + o
  int b = t >> 9;
  int o = t & (DIM - 1);
  float s = bias[o];
  #pragma unroll 4
  for (int c = 0; c < C; ++c) s += partial[(size_t)c * (BATCH * DIM) + t];
  Ht[o * BATCH + b] = f2bf(s);                     // transposed bf16 for layer-2 staging
}

__global__ void reduce_out(const float* __restrict__ partial, const float* __restrict__ bias,
                           float* __restrict__ out, int C) {
  int t = blockIdx.x * blockDim.x + threadIdx.x;   // 131072
  int o = t & (DIM - 1);
  float s = bias[o];
  #pragma unroll 4
  for (int c = 0; c < C; ++c) s += partial[(size_t)c * (BATCH * DIM) + t];
  out[t] = s;
}

extern "C" void kernel_launch(void* const* d_in, const int* in_sizes, int n_in,
                              void* d_out, int out_size, void* d_ws, size_t ws_size,
                              hipStream_t stream) {
  const float* x  = (const float*)d_in[0];
  const float* W0 = (const float*)d_in[1];
  const float* b0 = (const float*)d_in[2];
  const float* W1 = (const float*)d_in[3];
  const float* b1 = (const float*)d_in[4];
  float* out = (float*)d_out;

  char* ws = (char*)d_ws;
  unsigned* table    = (unsigned*)ws;                        // 525,312 B
  unsigned short* Xt = (unsigned short*)(ws + 525312);       // 262,144 B
  unsigned short* Ht = (unsigned short*)(ws + 787456);       // 262,144 B
  float* partial     = (float*)(ws + 1049600);               // C * 512 KiB

  size_t avail = (ws_size > 1049600) ? (ws_size - 1049600) : 0;
  int C = (int)(avail / ((size_t)BATCH * DIM * sizeof(float)));
  if (C > CMAX) C = CMAX;
  if (C < 1)   C = 1;

  build_table<<<dim3(512), dim3(256), 0, stream>>>(table);
  transpose_x<<<dim3(512), dim3(256), 0, stream>>>(x, Xt);

  qgemm<<<dim3(NTILES * C), dim3(512), 0, stream>>>(table, Xt, W0, partial, C);
  reduce_h<<<dim3(512), dim3(256), 0, stream>>>(partial, b0, Ht, C);

  qgemm<<<dim3(NTILES * C), dim3(512), 0, stream>>>(table, Ht, W1, partial, C);
  reduce_out<<<dim3(512), dim3(256), 0, stream>>>(partial, b1, out, C);
}

// Round 5
// 249.363 us; speedup vs baseline: 3.6887x; 1.0226x over previous
//
#include <hip/hip_runtime.h>

typedef short s16x8 __attribute__((ext_vector_type(8)));
typedef float f32x4 __attribute__((ext_vector_type(4)));

#define DIM     512
#define BATCH   256
#define NTRI    131328          // (512*512+512)/2
#define FDIM    131840          // 512 + NTRI
#define KBLOCKS 2060            // FDIM / 64
#define BN      64
#define NTILES  8               // 512 / BN
#define CCH     96              // K-chunks (multiple of 8 for XCD co-location)

__device__ __forceinline__ unsigned short f2bf(float f) {
  __bf16 h = (__bf16)f;                       // RNE hardware cvt
  return __builtin_bit_cast(unsigned short, h);
}
__device__ __forceinline__ float bf2f(unsigned short s) {
  union { unsigned u; float f; } v; v.u = (unsigned)s << 16; return v.f;
}
__device__ __forceinline__ unsigned pk2(float a, float b) {
  return (unsigned)f2bf(a) | ((unsigned)f2bf(b) << 16);
}
// bijective on aligned 8-runs and uniform over any 64-consecutive-m wave
__device__ __forceinline__ int swz(int m) { return (m ^ (m >> 2)) & 7; }

__device__ __forceinline__ void dma16(const void* g, void* l) {
  __builtin_amdgcn_global_load_lds(
      (const __attribute__((address_space(1))) void*)g,
      (__attribute__((address_space(3))) void*)l, 16, 0, 0);
}

// ---------- setup: pair index table, p -> (i<<16|j), triu order ----------
__global__ void build_table(unsigned* __restrict__ table) {
  int i = blockIdx.x;                          // 0..511
  int base = i * DIM - (i * (i - 1)) / 2;
  int len = DIM - i;
  for (int t = threadIdx.x; t < len; t += blockDim.x)
    table[base + t] = ((unsigned)i << 16) | (unsigned)(i + t);
}

// ---------- setup: x[256][512] f32 -> Xt[512][256] bf16 ----------
__global__ void transpose_x(const float* __restrict__ x, unsigned short* __restrict__ Xt) {
  int t = blockIdx.x * blockDim.x + threadIdx.x;   // 131072
  int r = t & (BATCH - 1);
  int c = t >> 8;
  Xt[c * BATCH + r] = f2bf(x[r * DIM + c]);
}

// ---------- feature materialization: per-kb 32KB pre-swizzled LDS images ----------
// Feat[kb] unit (m, slot) holds 8 bf16 features of k-group g = slot ^ swz(m).
__global__ __launch_bounds__(512)
void featgen(const unsigned* __restrict__ table,
             const unsigned short* __restrict__ Xt,   // [512][256] bf16
             uint4* __restrict__ Feat)                // [KBLOCKS][2048] uint4
{
  __shared__ uint4 img[2048];                  // 32 KB [m][slot]
  const int kb = blockIdx.x;
  const int tid = threadIdx.x;
  const int s8 = tid >> 6;                     // wave-uniform k-group
  const int lane = tid & 63;
  const int f0 = kb * 64 + s8 * 8;

  if (f0 < DIM) {                              // linear features (kb < 8)
    #pragma unroll
    for (int mb = 0; mb < 4; ++mb) {
      int m = mb * 64 + lane;
      unsigned short v[8];
      #pragma unroll
      for (int e = 0; e < 8; ++e) v[e] = Xt[(f0 + e) * BATCH + m];
      uint4 pk;
      pk.x = (unsigned)v[0] | ((unsigned)v[1] << 16);
      pk.y = (unsigned)v[2] | ((unsigned)v[3] << 16);
      pk.z = (unsigned)v[4] | ((unsigned)v[5] << 16);
      pk.w = (unsigned)v[6] | ((unsigned)v[7] << 16);
      img[m * 8 + (s8 ^ swz(m))] = pk;
    }
  } else {
    int p0 = f0 - DIM;
    unsigned t0 = table[p0], t7 = table[p0 + 7];
    if ((t0 >> 16) == (t7 >> 16)) {            // fast path: same i, contiguous j
      int i = (int)(t0 >> 16), j0 = (int)(t0 & 0xffffu);
      #pragma unroll
      for (int mb = 0; mb < 4; ++mb) {
        int m = mb * 64 + lane;
        float xi = bf2f(Xt[i * BATCH + m]);
        float pr[8];
        #pragma unroll
        for (int e = 0; e < 8; ++e) pr[e] = xi * bf2f(Xt[(j0 + e) * BATCH + m]);
        uint4 pk = make_uint4(pk2(pr[0], pr[1]), pk2(pr[2], pr[3]),
                              pk2(pr[4], pr[5]), pk2(pr[6], pr[7]));
        img[m * 8 + (s8 ^ swz(m))] = pk;
      }
    } else {                                   // run boundary (rare)
      unsigned tt[8];
      #pragma unroll
      for (int e = 0; e < 8; ++e) tt[e] = table[p0 + e];
      #pragma unroll
      for (int mb = 0; mb < 4; ++mb) {
        int m = mb * 64 + lane;
        float pr[8];
        #pragma unroll
        for (int e = 0; e < 8; ++e)
          pr[e] = bf2f(Xt[(tt[e] >> 16) * BATCH + m]) * bf2f(Xt[(tt[e] & 0xffffu) * BATCH + m]);
        uint4 pk = make_uint4(pk2(pr[0], pr[1]), pk2(pr[2], pr[3]),
                              pk2(pr[4], pr[5]), pk2(pr[6], pr[7]));
        img[m * 8 + (s8 ^ swz(m))] = pk;
      }
    }
  }
  __syncthreads();
  uint4* out = Feat + (size_t)kb * 2048;       // linear 32KB stream-out
  #pragma unroll
  for (int p = 0; p < 4; ++p) out[p * 512 + tid] = img[p * 512 + tid];
}

// ---------- GEMM: partial[chunk] = feat[256,Kc] @ W[n0:n0+64,:]^T ----------
__global__ __launch_bounds__(512, 4)
void qgemm(const uint4* __restrict__ Feat,      // pre-swizzled per-kb images
           const float* __restrict__ W,         // [512][131840] f32
           float* __restrict__ partial,         // [C][256][512]
           int C)
{
  __shared__ unsigned short As[BATCH * 64];     // 32 KB feature tile (DMA dest)
  __shared__ unsigned short Ws[64 * 64];        //  8 KB weight tile (bf16)
  const int chunk = blockIdx.x % C;             // C%8==0 -> chunk's 8 ntiles share an XCD
  const int ntile = blockIdx.x / C;
  const int kb0 = (KBLOCKS * chunk) / C;
  const int kb1 = (KBLOCKS * (chunk + 1)) / C;
  const int n0 = ntile * BN;
  const int tid = threadIdx.x;
  const int lane = tid & 63;
  const int wave = tid >> 6;
  const int wm = wave & 3;                      // 4 waves along M
  const int wn = wave >> 2;                     // 2 waves along N
  const int lm = lane & 15;
  const int lk = lane >> 4;

  // Ws staging role: 16 lanes cover 256B contiguous of one W row
  const int wr0 = tid >> 4;                     // 0..31 (+32 on 2nd iter)
  const int wc16 = tid & 15;

  f32x4 acc[4][2] = {};
  f32x4 wreg[2];

  // W prefetch for first iteration
  #pragma unroll
  for (int it = 0; it < 2; ++it)
    wreg[it] = *(const f32x4*)(W + (size_t)(n0 + wr0 + it * 32) * FDIM + kb0 * 64 + wc16 * 4);

  const char* fsrc0 = (const char*)Feat + tid * 16;
  char* adst = (char*)As + tid * 16;

  for (int kb = kb0; kb < kb1; ++kb) {
    // ---- issue As DMA (global -> LDS direct, linear; swizzle is in the data) ----
    const char* src = fsrc0 + (size_t)kb * 32768;
    #pragma unroll
    for (int p = 0; p < 4; ++p) dma16(src + p * 8192, adst + p * 8192);

    // ---- store W tile from regs loaded LAST iteration (latency long hidden) ----
    #pragma unroll
    for (int it = 0; it < 2; ++it) {
      int r = wr0 + it * 32;
      int slot = (wc16 >> 1) ^ swz(r);
      *(uint2*)((char*)Ws + r * 128 + slot * 16 + (wc16 & 1) * 8) =
          make_uint2(pk2(wreg[it][0], wreg[it][1]), pk2(wreg[it][2], wreg[it][3]));
    }
    // ---- prefetch next W into regs ----
    if (kb + 1 < kb1) {
      #pragma unroll
      for (int it = 0; it < 2; ++it)
        wreg[it] = *(const f32x4*)(W + (size_t)(n0 + wr0 + it * 32) * FDIM + (kb + 1) * 64 + wc16 * 4);
    }
    __syncthreads();                            // drains DMA (vmcnt) + Ws writes

    // ---- compute: 2 k-steps of 32, 4x2 fragments per wave ----
    #pragma unroll
    for (int ks = 0; ks < 2; ++ks) {
      s16x8 bfr[2], afr[4];
      #pragma unroll
      for (int nf = 0; nf < 2; ++nf) {
        int n = wn * 32 + nf * 16 + lm;
        int slot = (ks * 4 + lk) ^ swz(n);
        bfr[nf] = *(const s16x8*)((const char*)Ws + n * 128 + slot * 16);
      }
      #pragma unroll
      for (int mf = 0; mf < 4; ++mf) {
        int mm = wm * 64 + mf * 16 + lm;
        int slot = (ks * 4 + lk) ^ swz(mm);
        afr[mf] = *(const s16x8*)((const char*)As + mm * 128 + slot * 16);
      }
      #pragma unroll
      for (int mf = 0; mf < 4; ++mf)
        #pragma unroll
        for (int nf = 0; nf < 2; ++nf)
          acc[mf][nf] = __builtin_amdgcn_mfma_f32_16x16x32_bf16(afr[mf], bfr[nf], acc[mf][nf], 0, 0, 0);
    }
    __syncthreads();
  }

  // ---- write partial tile ----
  float* pout = partial + (size_t)chunk * (BATCH * DIM);
  #pragma unroll
  for (int mf = 0; mf < 4; ++mf) {
    #pragma unroll
    for (int nf = 0; nf < 2; ++nf) {
      int mrow = wm * 64 + mf * 16 + lk * 4;    // C/D: col=lane&15, row=(lane>>4)*4+reg
      int ncol = n0 + wn * 32 + nf * 16 + lm;
      #pragma unroll
      for (int r = 0; r < 4; ++r)
        pout[(size_t)(mrow + r) * DIM + ncol] = acc[mf][nf][r];
    }
  }
}

// ---------- reductions ----------
__global__ void reduce_h(const float* __restrict__ partial, const float* __restrict__ bias,
                         unsigned short* __restrict__ Ht, int C) {
  int t = blockIdx.x * blockDim.x + threadIdx.x;   // 131072, t = b*512 + o
  int b = t >> 9;
  int o = t & (DIM - 1);
  float s = bias[o];
  #pragma unroll 4
  for (int c = 0; c < C; ++c) s += partial[(size_t)c * (BATCH * DIM) + t];
  Ht[o * BATCH + b] = f2bf(s);                     // transposed bf16 for layer-2 featgen
}

__global__ void reduce_out(const float* __restrict__ partial, const float* __restrict__ bias,
                           float* __restrict__ out, int C) {
  int t = blockIdx.x * blockDim.x + threadIdx.x;   // 131072
  int o = t & (DIM - 1);
  float s = bias[o];
  #pragma unroll 4
  for (int c = 0; c < C; ++c) s += partial[(size_t)c * (BATCH * DIM) + t];
  out[t] = s;
}

extern "C" void kernel_launch(void* const* d_in, const int* in_sizes, int n_in,
                              void* d_out, int out_size, void* d_ws, size_t ws_size,
                              hipStream_t stream) {
  const float* x  = (const float*)d_in[0];
  const float* W0 = (const float*)d_in[1];
  const float* b0 = (const float*)d_in[2];
  const float* W1 = (const float*)d_in[3];
  const float* b1 = (const float*)d_in[4];
  float* out = (float*)d_out;

  char* ws = (char*)d_ws;
  unsigned* table    = (unsigned*)ws;                        // 525,312 B
  unsigned short* Xt = (unsigned short*)(ws + 525312);       // 262,144 B
  unsigned short* Ht = (unsigned short*)(ws + 787456);       // 262,144 B
  uint4* Feat        = (uint4*)(ws + 1049600);               // 67,502,080 B (2060*32KB)
  size_t feat_end    = 1049600 + (size_t)KBLOCKS * 32768;
  float* partial     = (float*)(ws + feat_end);              // C * 512 KiB

  size_t avail = (ws_size > feat_end) ? (ws_size - feat_end) : 0;
  int C = (int)(avail / ((size_t)BATCH * DIM * sizeof(float)));
  if (C > CCH) C = CCH;
  if (C < 1)  C = 1;

  build_table<<<dim3(512), dim3(256), 0, stream>>>(table);
  transpose_x<<<dim3(512), dim3(256), 0, stream>>>(x, Xt);

  featgen<<<dim3(KBLOCKS), dim3(512), 0, stream>>>(table, Xt, Feat);
  qgemm<<<dim3(NTILES * C), dim3(512), 0, stream>>>(Feat, W0, partial, C);
  reduce_h<<<dim3(512), dim3(256), 0, stream>>>(partial, b0, Ht, C);

  featgen<<<dim3(KBLOCKS), dim3(512), 0, stream>>>(table, Ht, Feat);
  qgemm<<<dim3(NTILES * C), dim3(512), 0, stream>>>(Feat, W1, partial, C);
  reduce_out<<<dim3(512), dim3(256), 0, stream>>>(partial, b1, out, C);
}

// Round 6
// 232.262 us; speedup vs baseline: 3.9602x; 1.0736x over previous
//
#include <hip/hip_runtime.h>

typedef short s16x8 __attribute__((ext_vector_type(8)));
typedef float f32x4 __attribute__((ext_vector_type(4)));

#define DIM     512
#define BATCH   256
#define NTRI    131328          // (512*512+512)/2
#define FDIM    131840          // 512 + NTRI
#define KBLOCKS 2060            // FDIM / 64
#define BN      64
#define NTILES  8               // 512 / BN
#define CCH     64              // K-chunks: grid 512 = exactly 2 wg/CU, %8==0

__device__ __forceinline__ unsigned short f2bf(float f) {
  __bf16 h = (__bf16)f;                       // RNE hardware cvt
  return __builtin_bit_cast(unsigned short, h);
}
__device__ __forceinline__ float bf2f(unsigned short s) {
  union { unsigned u; float f; } v; v.u = (unsigned)s << 16; return v.f;
}
__device__ __forceinline__ unsigned pk2(float a, float b) {
  return (unsigned)f2bf(a) | ((unsigned)f2bf(b) << 16);
}
// bijective on aligned 8-runs and uniform over any 64-consecutive-m wave
__device__ __forceinline__ int swz(int m) { return (m ^ (m >> 2)) & 7; }

__device__ __forceinline__ void dma16(const void* g, void* l) {
  __builtin_amdgcn_global_load_lds(
      (const __attribute__((address_space(1))) void*)g,
      (__attribute__((address_space(3))) void*)l, 16, 0, 0);
}

// ---------- setup: pair index table, p -> (i<<16|j), triu order ----------
__global__ void build_table(unsigned* __restrict__ table) {
  int i = blockIdx.x;                          // 0..511
  int base = i * DIM - (i * (i - 1)) / 2;
  int len = DIM - i;
  for (int t = threadIdx.x; t < len; t += blockDim.x)
    table[base + t] = ((unsigned)i << 16) | (unsigned)(i + t);
}

// ---------- setup: x[256][512] f32 -> Xt[512][256] bf16 ----------
__global__ void transpose_x(const float* __restrict__ x, unsigned short* __restrict__ Xt) {
  int t = blockIdx.x * blockDim.x + threadIdx.x;   // 131072
  int r = t & (BATCH - 1);
  int c = t >> 8;
  Xt[c * BATCH + r] = f2bf(x[r * DIM + c]);
}

// ---------- feature materialization: per-kb 32KB pre-swizzled LDS images ----------
__global__ __launch_bounds__(512)
void featgen(const unsigned* __restrict__ table,
             const unsigned short* __restrict__ Xt,   // [512][256] bf16
             uint4* __restrict__ Feat)                // [KBLOCKS][2048] uint4
{
  __shared__ uint4 img[2048];                  // 32 KB [m][slot]
  const int kb = blockIdx.x;
  const int tid = threadIdx.x;
  const int s8 = tid >> 6;                     // wave-uniform k-group
  const int lane = tid & 63;
  const int f0 = kb * 64 + s8 * 8;

  if (f0 < DIM) {                              // linear features (kb < 8)
    #pragma unroll
    for (int mb = 0; mb < 4; ++mb) {
      int m = mb * 64 + lane;
      unsigned short v[8];
      #pragma unroll
      for (int e = 0; e < 8; ++e) v[e] = Xt[(f0 + e) * BATCH + m];
      uint4 pk;
      pk.x = (unsigned)v[0] | ((unsigned)v[1] << 16);
      pk.y = (unsigned)v[2] | ((unsigned)v[3] << 16);
      pk.z = (unsigned)v[4] | ((unsigned)v[5] << 16);
      pk.w = (unsigned)v[6] | ((unsigned)v[7] << 16);
      img[m * 8 + (s8 ^ swz(m))] = pk;
    }
  } else {
    int p0 = f0 - DIM;
    unsigned t0 = table[p0], t7 = table[p0 + 7];
    if ((t0 >> 16) == (t7 >> 16)) {            // fast path: same i, contiguous j
      int i = (int)(t0 >> 16), j0 = (int)(t0 & 0xffffu);
      #pragma unroll
      for (int mb = 0; mb < 4; ++mb) {
        int m = mb * 64 + lane;
        float xi = bf2f(Xt[i * BATCH + m]);
        float pr[8];
        #pragma unroll
        for (int e = 0; e < 8; ++e) pr[e] = xi * bf2f(Xt[(j0 + e) * BATCH + m]);
        uint4 pk = make_uint4(pk2(pr[0], pr[1]), pk2(pr[2], pr[3]),
                              pk2(pr[4], pr[5]), pk2(pr[6], pr[7]));
        img[m * 8 + (s8 ^ swz(m))] = pk;
      }
    } else {                                   // run boundary (rare)
      unsigned tt[8];
      #pragma unroll
      for (int e = 0; e < 8; ++e) tt[e] = table[p0 + e];
      #pragma unroll
      for (int mb = 0; mb < 4; ++mb) {
        int m = mb * 64 + lane;
        float pr[8];
        #pragma unroll
        for (int e = 0; e < 8; ++e)
          pr[e] = bf2f(Xt[(tt[e] >> 16) * BATCH + m]) * bf2f(Xt[(tt[e] & 0xffffu) * BATCH + m]);
        uint4 pk = make_uint4(pk2(pr[0], pr[1]), pk2(pr[2], pr[3]),
                              pk2(pr[4], pr[5]), pk2(pr[6], pr[7]));
        img[m * 8 + (s8 ^ swz(m))] = pk;
      }
    }
  }
  __syncthreads();
  uint4* out = Feat + (size_t)kb * 2048;       // linear 32KB stream-out
  #pragma unroll
  for (int p = 0; p < 4; ++p) out[p * 512 + tid] = img[p * 512 + tid];
}

// ---------- GEMM: partial[chunk] = feat[256,Kc] @ W[n0:n0+64,:]^T ----------
// Double-buffered pipeline: DMA/W-load for t+1 stay in flight across both raw barriers.
__global__ __launch_bounds__(512, 4)
void qgemm(const uint4* __restrict__ Feat,      // pre-swizzled per-kb images
           const float* __restrict__ W,         // [512][131840] f32
           float* __restrict__ partial,         // [C][256][512]
           int C)
{
  __shared__ unsigned short As[2 * BATCH * 64]; // 64 KB double-buffered feature tiles
  __shared__ unsigned short Ws[2 * 64 * 64];    // 16 KB double-buffered weight tiles
  const int chunk = blockIdx.x % C;             // C%8==0 -> chunk's 8 ntiles share an XCD
  const int ntile = blockIdx.x / C;
  const int kb0 = (KBLOCKS * chunk) / C;
  const int kb1 = (KBLOCKS * (chunk + 1)) / C;
  const int n0 = ntile * BN;
  const int tid = threadIdx.x;
  const int lane = tid & 63;
  const int wave = tid >> 6;
  const int wm = wave & 3;                      // 4 waves along M
  const int wn = wave >> 2;                     // 2 waves along N
  const int lm = lane & 15;
  const int lk = lane >> 4;

  const int wr0 = tid >> 4;                     // Ws staging: 16 lanes = 256B of one W row
  const int wc16 = tid & 15;

  f32x4 acc[4][2] = {};
  f32x4 wregC[2], wregN[2];

  const char* fsrc0 = (const char*)Feat + tid * 16;
  char* adst0 = (char*)As + tid * 16;
  const float* wp0 = W + (size_t)(n0 + wr0) * FDIM + wc16 * 4;
  const size_t wrow32 = (size_t)32 * FDIM;

  // ---- prologue: tile kb0 in flight ----
  {
    const char* src = fsrc0 + (size_t)kb0 * 32768;
    #pragma unroll
    for (int p = 0; p < 4; ++p) dma16(src + p * 8192, adst0 + p * 8192);
    #pragma unroll
    for (int it = 0; it < 2; ++it)
      wregC[it] = *(const f32x4*)(wp0 + it * wrow32 + (size_t)kb0 * 64);
  }

  // ---- steady loop (last iteration peeled) ----
  for (int kb = kb0; kb < kb1 - 1; ++kb) {
    const int pc = (kb - kb0) & 1;
    // issue next tile: 4 DMA + 2 W loads (6 VMEM, stay in flight through compute)
    {
      const char* src = fsrc0 + (size_t)(kb + 1) * 32768;
      char* dst = adst0 + (pc ^ 1) * 32768;
      #pragma unroll
      for (int p = 0; p < 4; ++p) dma16(src + p * 8192, dst + p * 8192);
      #pragma unroll
      for (int it = 0; it < 2; ++it)
        wregN[it] = *(const f32x4*)(wp0 + it * wrow32 + (size_t)(kb + 1) * 64);
    }
    __builtin_amdgcn_sched_barrier(0);          // pin issues above the Ws store
    // store Ws(t): compiler emits counted vmcnt (retires DMA(t)+W(t), keeps t+1 in flight)
    #pragma unroll
    for (int it = 0; it < 2; ++it) {
      int r = wr0 + it * 32;
      int slot = (wc16 >> 1) ^ swz(r);
      *(uint2*)((char*)Ws + pc * 8192 + r * 128 + slot * 16 + (wc16 & 1) * 8) =
          make_uint2(pk2(wregC[it][0], wregC[it][1]), pk2(wregC[it][2], wregC[it][3]));
    }
    asm volatile("s_waitcnt lgkmcnt(0)" ::: "memory");
    __builtin_amdgcn_sched_barrier(0);
    __builtin_amdgcn_s_barrier();               // As(t)/Ws(t) visible to all waves
    // compute(t)
    {
      const char* asb = (const char*)As + pc * 32768;
      const char* wsb = (const char*)Ws + pc * 8192;
      #pragma unroll
      for (int ks = 0; ks < 2; ++ks) {
        s16x8 bfr[2], afr[4];
        #pragma unroll
        for (int nf = 0; nf < 2; ++nf) {
          int n = wn * 32 + nf * 16 + lm;
          int slot = (ks * 4 + lk) ^ swz(n);
          bfr[nf] = *(const s16x8*)(wsb + n * 128 + slot * 16);
        }
        #pragma unroll
        for (int mf = 0; mf < 4; ++mf) {
          int mm = wm * 64 + mf * 16 + lm;
          int slot = (ks * 4 + lk) ^ swz(mm);
          afr[mf] = *(const s16x8*)(asb + mm * 128 + slot * 16);
        }
        #pragma unroll
        for (int mf = 0; mf < 4; ++mf)
          #pragma unroll
          for (int nf = 0; nf < 2; ++nf)
            acc[mf][nf] = __builtin_amdgcn_mfma_f32_16x16x32_bf16(afr[mf], bfr[nf], acc[mf][nf], 0, 0, 0);
      }
    }
    __builtin_amdgcn_s_barrier();               // protect buffers before next iter's writes
    wregC[0] = wregN[0]; wregC[1] = wregN[1];
  }

  // ---- peeled last iteration ----
  {
    const int pc = (kb1 - 1 - kb0) & 1;
    #pragma unroll
    for (int it = 0; it < 2; ++it) {
      int r = wr0 + it * 32;
      int slot = (wc16 >> 1) ^ swz(r);
      *(uint2*)((char*)Ws + pc * 8192 + r * 128 + slot * 16 + (wc16 & 1) * 8) =
          make_uint2(pk2(wregC[it][0], wregC[it][1]), pk2(wregC[it][2], wregC[it][3]));
    }
    asm volatile("s_waitcnt lgkmcnt(0)" ::: "memory");
    __builtin_amdgcn_s_barrier();
    const char* asb = (const char*)As + pc * 32768;
    const char* wsb = (const char*)Ws + pc * 8192;
    #pragma unroll
    for (int ks = 0; ks < 2; ++ks) {
      s16x8 bfr[2], afr[4];
      #pragma unroll
      for (int nf = 0; nf < 2; ++nf) {
        int n = wn * 32 + nf * 16 + lm;
        int slot = (ks * 4 + lk) ^ swz(n);
        bfr[nf] = *(const s16x8*)(wsb + n * 128 + slot * 16);
      }
      #pragma unroll
      for (int mf = 0; mf < 4; ++mf) {
        int mm = wm * 64 + mf * 16 + lm;
        int slot = (ks * 4 + lk) ^ swz(mm);
        afr[mf] = *(const s16x8*)(asb + mm * 128 + slot * 16);
      }
      #pragma unroll
      for (int mf = 0; mf < 4; ++mf)
        #pragma unroll
        for (int nf = 0; nf < 2; ++nf)
          acc[mf][nf] = __builtin_amdgcn_mfma_f32_16x16x32_bf16(afr[mf], bfr[nf], acc[mf][nf], 0, 0, 0);
    }
  }

  // ---- write partial tile ----
  float* pout = partial + (size_t)chunk * (BATCH * DIM);
  #pragma unroll
  for (int mf = 0; mf < 4; ++mf) {
    #pragma unroll
    for (int nf = 0; nf < 2; ++nf) {
      int mrow = wm * 64 + mf * 16 + lk * 4;    // C/D: col=lane&15, row=(lane>>4)*4+reg
      int ncol = n0 + wn * 32 + nf * 16 + lm;
      #pragma unroll
      for (int r = 0; r < 4; ++r)
        pout[(size_t)(mrow + r) * DIM + ncol] = acc[mf][nf][r];
    }
  }
}

// ---------- reductions ----------
__global__ void reduce_h(const float* __restrict__ partial, const float* __restrict__ bias,
                         unsigned short* __restrict__ Ht, int C) {
  int t = blockIdx.x * blockDim.x + threadIdx.x;   // 131072, t = b*512 + o
  int b = t >> 9;
  int o = t & (DIM - 1);
  float s = bias[o];
  #pragma unroll 4
  for (int c = 0; c < C; ++c) s += partial[(size_t)c * (BATCH * DIM) + t];
  Ht[o * BATCH + b] = f2bf(s);                     // transposed bf16 for layer-2 featgen
}

__global__ void reduce_out(const float* __restrict__ partial, const float* __restrict__ bias,
                           float* __restrict__ out, int C) {
  int t = blockIdx.x * blockDim.x + threadIdx.x;   // 131072
  int o = t & (DIM - 1);
  float s = bias[o];
  #pragma unroll 4
  for (int c = 0; c < C; ++c) s += partial[(size_t)c * (BATCH * DIM) + t];
  out[t] = s;
}

extern "C" void kernel_launch(void* const* d_in, const int* in_sizes, int n_in,
                              void* d_out, int out_size, void* d_ws, size_t ws_size,
                              hipStream_t stream) {
  const float* x  = (const float*)d_in[0];
  const float* W0 = (const float*)d_in[1];
  const float* b0 = (const float*)d_in[2];
  const float* W1 = (const float*)d_in[3];
  const float* b1 = (const float*)d_in[4];
  float* out = (float*)d_out;

  char* ws = (char*)d_ws;
  unsigned* table    = (unsigned*)ws;                        // 525,312 B
  unsigned short* Xt = (unsigned short*)(ws + 525312);       // 262,144 B
  unsigned short* Ht = (unsigned short*)(ws + 787456);       // 262,144 B
  uint4* Feat        = (uint4*)(ws + 1049600);               // 67,502,080 B (2060*32KB)
  size_t feat_end    = 1049600 + (size_t)KBLOCKS * 32768;
  float* partial     = (float*)(ws + feat_end);              // C * 512 KiB

  size_t avail = (ws_size > feat_end) ? (ws_size - feat_end) : 0;
  int C = (int)(avail / ((size_t)BATCH * DIM * sizeof(float)));
  if (C > CCH) C = CCH;
  if (C < 1)  C = 1;

  build_table<<<dim3(512), dim3(256), 0, stream>>>(table);
  transpose_x<<<dim3(512), dim3(256), 0, stream>>>(x, Xt);

  featgen<<<dim3(KBLOCKS), dim3(512), 0, stream>>>(table, Xt, Feat);
  qgemm<<<dim3(NTILES * C), dim3(512), 0, stream>>>(Feat, W0, partial, C);
  reduce_h<<<dim3(512), dim3(256), 0, stream>>>(partial, b0, Ht, C);

  featgen<<<dim3(KBLOCKS), dim3(512), 0, stream>>>(table, Ht, Feat);
  qgemm<<<dim3(NTILES * C), dim3(512), 0, stream>>>(Feat, W1, partial, C);
  reduce_out<<<dim3(512), dim3(256), 0, stream>>>(partial, b1, out, C);
}